// Round 6
// baseline (102.023 us; speedup 1.0000x reference)
//
#include <hip/hip_runtime.h>
#include <math.h>

#define BATCH 512
#define DIN   5120
#define DST   16
#define RK    160
#define NJ    192
#define NZ    32    // split-K slices

// ---------------------------------------------------------------------------
// Kernel 1: P[j,b] = sum_d W[j,d] * x[b,d]  (j<160: W_dt_rank, then B, C).
// Split-K, atomics-free. grid (3,8,32), block 256, 10 k-iters of 16.
// ---------------------------------------------------------------------------
__global__ __launch_bounds__(256) void k_proj(
    const float* __restrict__ x, const float* __restrict__ Wdtr,
    const float* __restrict__ WB, const float* __restrict__ WC,
    float* __restrict__ part)
{
  const int t  = threadIdx.x;
  const int j0 = blockIdx.x * 64;
  const int b0 = blockIdx.y * 64;
  const int k_start = blockIdx.z * 160;

  __shared__ float sW[16][68];   // [k][j]
  __shared__ float sX[16][68];   // [k][b]

  const int tj = t & 15, tb = t >> 4;
  const int srow = t >> 2, sq = t & 3;

  const int j = j0 + srow;
  const float* wrow;
  if (j < RK)            wrow = Wdtr + (size_t)j * DIN;
  else if (j < RK + DST) wrow = WB   + (size_t)(j - RK) * DIN;
  else                   wrow = WC   + (size_t)(j - RK - DST) * DIN;
  const float* xrow = x + (size_t)(b0 + srow) * DIN;

  float acc[4][4] = {};

  float4 wv = *(const float4*)(wrow + k_start + sq * 4);
  float4 xv = *(const float4*)(xrow + k_start + sq * 4);

  for (int kc = 0; kc < 10; ++kc) {
    __syncthreads();
    sW[sq*4+0][srow] = wv.x; sW[sq*4+1][srow] = wv.y;
    sW[sq*4+2][srow] = wv.z; sW[sq*4+3][srow] = wv.w;
    sX[sq*4+0][srow] = xv.x; sX[sq*4+1][srow] = xv.y;
    sX[sq*4+2][srow] = xv.z; sX[sq*4+3][srow] = xv.w;
    __syncthreads();
    if (kc < 9) {
      const int k = k_start + (kc + 1) * 16 + sq * 4;
      wv = *(const float4*)(wrow + k);
      xv = *(const float4*)(xrow + k);
    }
#pragma unroll
    for (int kk = 0; kk < 16; ++kk) {
      const float4 wf = *(const float4*)&sW[kk][tj*4];
      const float4 xf = *(const float4*)&sX[kk][tb*4];
      const float w[4] = {wf.x, wf.y, wf.z, wf.w};
      const float xr[4] = {xf.x, xf.y, xf.z, xf.w};
#pragma unroll
      for (int a = 0; a < 4; ++a)
#pragma unroll
        for (int c = 0; c < 4; ++c)
          acc[a][c] = fmaf(w[a], xr[c], acc[a][c]);
    }
  }

  float* pb = part + ((((size_t)blockIdx.z * 3 + blockIdx.x) * 8 + blockIdx.y) << 12) + t * 16;
#pragma unroll
  for (int a = 0; a < 4; ++a)
    *(float4*)(pb + a * 4) = make_float4(acc[a][0], acc[a][1], acc[a][2], acc[a][3]);
}

// ---------------------------------------------------------------------------
// Kernel 1b: sum 32 k-slice partials, scatter into dtr/B/C. 384 blocks.
// ---------------------------------------------------------------------------
__global__ __launch_bounds__(256) void k_reduce(
    const float* __restrict__ part,
    float* __restrict__ o_dtr, float* __restrict__ o_B, float* __restrict__ o_C)
{
  const int g = blockIdx.x * 256 + threadIdx.x;
  const int f  = g & 4095;
  const int bx = (g >> 12) & 7;
  const int jx = g >> 15;

  float s = 0.f;
#pragma unroll
  for (int z = 0; z < NZ; ++z)
    s += part[(((size_t)(z * 3 + jx) * 8 + bx) << 12) + f];

  const int t = f >> 4, a = (f >> 2) & 3, c = f & 3;
  const int jj = jx * 64 + (t & 15) * 4 + a;
  const int bb = bx * 64 + (t >> 4) * 4 + c;
  if (jj < RK)            o_dtr[(size_t)bb * RK + jj] = s;
  else if (jj < RK + DST) o_B[(size_t)bb * DST + (jj - RK)] = s;
  else                    o_C[(size_t)bb * DST + (jj - RK - DST)] = s;
}

// ---------------------------------------------------------------------------
// Kernel 2: dt = softplus(dtr @ Wdt^T + bdt). 128d x 128b tile, 8x8/thread
// (0.5 B LDS per FLOP -> LDS and VALU balanced). grid (40,4), block 256.
// ---------------------------------------------------------------------------
__global__ __launch_bounds__(256) void k_dt(
    const float* __restrict__ dtr, const float* __restrict__ Wdt,
    const float* __restrict__ bdt, float* __restrict__ dt)
{
  const int t  = threadIdx.x;
  const int d0 = blockIdx.x * 128;
  const int b0 = blockIdx.y * 128;

  __shared__ float sW[32][132];   // [k][d]
  __shared__ float sD[32][132];   // [k][b]

  const int tdl = t & 15, tbl = t >> 4;

  // staging: 128 rows x 8 float4 per matrix = 1024 float4; 4 per thread,
  // l = i*256 + t  (wave-coalesced per i)
  float4 wbuf[4], dbuf[4];
#pragma unroll
  for (int i = 0; i < 4; ++i) {
    const int l = i * 256 + t;
    wbuf[i] = *(const float4*)&Wdt[(size_t)(d0 + (l >> 3)) * RK + (l & 7) * 4];
    dbuf[i] = *(const float4*)&dtr[(size_t)(b0 + (l >> 3)) * RK + (l & 7) * 4];
  }

  float acc[8][8] = {};

  for (int rc = 0; rc < 5; ++rc) {
    __syncthreads();
#pragma unroll
    for (int i = 0; i < 4; ++i) {
      const int l = i * 256 + t;
      const int r = l >> 3, c = (l & 7) * 4;
      sW[c+0][r] = wbuf[i].x; sW[c+1][r] = wbuf[i].y;
      sW[c+2][r] = wbuf[i].z; sW[c+3][r] = wbuf[i].w;
      sD[c+0][r] = dbuf[i].x; sD[c+1][r] = dbuf[i].y;
      sD[c+2][r] = dbuf[i].z; sD[c+3][r] = dbuf[i].w;
    }
    __syncthreads();
    if (rc < 4) {
      const int k = (rc + 1) * 32;
#pragma unroll
      for (int i = 0; i < 4; ++i) {
        const int l = i * 256 + t;
        wbuf[i] = *(const float4*)&Wdt[(size_t)(d0 + (l >> 3)) * RK + k + (l & 7) * 4];
        dbuf[i] = *(const float4*)&dtr[(size_t)(b0 + (l >> 3)) * RK + k + (l & 7) * 4];
      }
    }
#pragma unroll
    for (int kk = 0; kk < 32; ++kk) {
      float w[8], dd[8];
      *(float4*)&w[0]  = *(const float4*)&sW[kk][tdl*8];
      *(float4*)&w[4]  = *(const float4*)&sW[kk][tdl*8+4];
      *(float4*)&dd[0] = *(const float4*)&sD[kk][tbl*8];
      *(float4*)&dd[4] = *(const float4*)&sD[kk][tbl*8+4];
#pragma unroll
      for (int a = 0; a < 8; ++a)
#pragma unroll
        for (int c = 0; c < 8; ++c)
          acc[a][c] = fmaf(w[a], dd[c], acc[a][c]);
    }
  }

  float bv[8];
  *(float4*)&bv[0] = *(const float4*)&bdt[d0 + tdl*8];
  *(float4*)&bv[4] = *(const float4*)&bdt[d0 + tdl*8 + 4];
#pragma unroll
  for (int c = 0; c < 8; ++c) {
    const int b = b0 + tbl*8 + c;
    float o[8];
#pragma unroll
    for (int a = 0; a < 8; ++a) {
      const float pre = acc[a][c] + bv[a];
      o[a] = (pre > 20.f) ? pre : log1pf(__expf(pre));
    }
    *(float4*)&dt[(size_t)b * DIN + d0 + tdl*8]     = *(float4*)&o[0];
    *(float4*)&dt[(size_t)b * DIN + d0 + tdl*8 + 4] = *(float4*)&o[4];
  }
}

// ---------------------------------------------------------------------------
// Kernel 3: streaming state update + y, coalesced h, grid-stride x5 for ILP.
// Quad of lanes per (b,d); 8192 blocks x 256 thr x 5 iters = 2.62M (b,d).
// ---------------------------------------------------------------------------
#define YGRID 8192
__global__ __launch_bounds__(256) void k_y(
    const float* __restrict__ dt, const float* __restrict__ Bc,
    const float* __restrict__ Cc, const float* __restrict__ A,
    const float* __restrict__ Dp, const float* __restrict__ x,
    const float* __restrict__ h,  float* __restrict__ y)
{
  const int q = threadIdx.x & 3;
  const int base = blockIdx.x * 64 + (threadIdx.x >> 2);

#pragma unroll
  for (int it = 0; it < 5; ++it) {
    const int g = base + it * (YGRID * 64);
    const int b = g / DIN;
    const int d = g - b * DIN;

    const float dtv = dt[g];
    const float xv  = x[g];
    const float dtx = dtv * xv;

    const float4 h4 = *(const float4*)(h  + (size_t)g * DST + q * 4);
    const float4 A4 = *(const float4*)(A  + (size_t)d * DST + q * 4);
    const float4 B4 = *(const float4*)(Bc + (size_t)b * DST + q * 4);
    const float4 C4 = *(const float4*)(Cc + (size_t)b * DST + q * 4);

    const float dA0 = __expf(A4.x * dtv);
    const float dA1 = __expf(A4.y * dtv);
    const float dA2 = __expf(A4.z * dtv);
    const float dA3 = __expf(A4.w * dtv);
    const float hn0 = fmaf(dA0, h4.x, dtx * B4.x);
    const float hn1 = fmaf(dA1, h4.y, dtx * B4.y);
    const float hn2 = fmaf(dA2, h4.z, dtx * B4.z);
    const float hn3 = fmaf(dA3, h4.w, dtx * B4.w);
    float p = hn0 * C4.x + hn1 * C4.y + hn2 * C4.z + hn3 * C4.w;

    p += __shfl_xor(p, 1);
    p += __shfl_xor(p, 2);
    if (q == 0) y[g] = fmaf(Dp[d], xv, p);
  }
}

extern "C" void kernel_launch(void* const* d_in, const int* in_sizes, int n_in,
                              void* d_out, int out_size, void* d_ws, size_t ws_size,
                              hipStream_t stream) {
  const float* x    = (const float*)d_in[0];
  const float* Wdtr = (const float*)d_in[1];
  const float* Wdt  = (const float*)d_in[2];
  const float* bdt  = (const float*)d_in[3];
  const float* WB   = (const float*)d_in[4];
  const float* WC   = (const float*)d_in[5];
  const float* A    = (const float*)d_in[6];
  const float* Dp   = (const float*)d_in[7];
  const float* h    = (const float*)d_in[8];
  float* y = (float*)d_out;

  float* ws_part = (float*)d_ws;
  float* ws_dtr  = ws_part + (size_t)NZ * 3 * 8 * 4096;
  float* ws_B    = ws_dtr + (size_t)BATCH * RK;
  float* ws_C    = ws_B   + (size_t)BATCH * DST;
  float* ws_dt   = ws_C   + (size_t)BATCH * DST;

  k_proj<<<dim3(3, 8, NZ), 256, 0, stream>>>(x, Wdtr, WB, WC, ws_part);
  k_reduce<<<dim3(384), 256, 0, stream>>>(ws_part, ws_dtr, ws_B, ws_C);
  k_dt<<<dim3(40, 4), 256, 0, stream>>>(ws_dtr, Wdt, bdt, ws_dt);
  k_y<<<dim3(YGRID), 256, 0, stream>>>(ws_dt, ws_B, ws_C, A, Dp, x, h, y);
}

// Round 7
// 68.221 us; speedup vs baseline: 1.4955x; 1.4955x over previous
//
#include <hip/hip_runtime.h>
#include <math.h>

#define BATCH 512
#define DIN   5120
#define DST   16
#define RK    160
#define NJ    192     // 160 dt_rank + 16 B + 16 C
#define NZ1   16      // GEMM1 split-K slices (K=320 each, 10 MFMA steps)

typedef __attribute__((ext_vector_type(8))) __bf16 bf16x8;
typedef __attribute__((ext_vector_type(4))) float f32x4;
typedef __attribute__((ext_vector_type(8))) unsigned short ushort8;

// ws byte offsets (all 16B aligned)
#define OFF_XP    0u          // xP   [640 k8][512 b][8]  bf16  (5,242,880 B)
#define OFF_WP    5242880u    // WP   [640 k8][192 j][8]  bf16  (1,966,080 B)
#define OFF_WDTP  7208960u    // WdtP [20 k8][5120 d][8]  bf16  (1,638,400 B)
#define OFF_PART  8847360u    // part1[6144 task][256]    f32   (6,291,456 B)
#define OFF_DTRP  15138816u   // dtrP [20 k8][512 b][8]   bf16  (163,840 B)
#define OFF_B     15302656u   // Bc   [512][16] f32
#define OFF_C     15335424u   // Cc   [512][16] f32
#define OFF_DT    15368192u   // dt   [512][5120] f32

__device__ __forceinline__ unsigned short f2bf(float f) {
  unsigned int u = __float_as_uint(f);
  u = (u + 0x7FFFu + ((u >> 16) & 1u)) >> 16;   // RNE
  return (unsigned short)u;
}

// ---------------------------------------------------------------------------
// k_prep: pack bf16 operands.
//  job1 (1280 blocks): xP[k8][b][8]   from x[b][k]
//  job2 ( 480 blocks): WP[k8][j][8]   from {W_dt_rank; W_B; W_C}[j][k]
//  job3 ( 400 blocks): WdtP[k8][d][8] from W_dt[d][k]
// ---------------------------------------------------------------------------
#define N1 (512*640)
#define N2 (192*640)
__global__ __launch_bounds__(256) void k_prep(
    const float* __restrict__ x, const float* __restrict__ Wdtr,
    const float* __restrict__ WB, const float* __restrict__ WC,
    const float* __restrict__ Wdt, char* __restrict__ ws)
{
  const int tid = blockIdx.x * 256 + threadIdx.x;
  const float* src; unsigned long long dst_idx;
  if (tid < N1) {
    const int b = tid / 640, k8 = tid - b * 640;
    src = x + (size_t)b * DIN + k8 * 8;
    dst_idx = (OFF_XP >> 4) + (size_t)k8 * 512 + b;
  } else if (tid < N1 + N2) {
    const int i = tid - N1;
    const int j = i / 640, k8 = i - j * 640;
    const float* row;
    if (j < RK)            row = Wdtr + (size_t)j * DIN;
    else if (j < RK + DST) row = WB   + (size_t)(j - RK) * DIN;
    else                   row = WC   + (size_t)(j - RK - DST) * DIN;
    src = row + k8 * 8;
    dst_idx = (OFF_WP >> 4) + (size_t)k8 * 192 + j;
  } else {
    const int i = tid - N1 - N2;          // < 5120*20
    const int d = i / 20, k8 = i - d * 20;
    src = Wdt + (size_t)d * RK + k8 * 8;
    dst_idx = (OFF_WDTP >> 4) + (size_t)k8 * 5120 + d;
  }
  const float4 f0 = *(const float4*)(src);
  const float4 f1 = *(const float4*)(src + 4);
  ushort8 o;
  o[0]=f2bf(f0.x); o[1]=f2bf(f0.y); o[2]=f2bf(f0.z); o[3]=f2bf(f0.w);
  o[4]=f2bf(f1.x); o[5]=f2bf(f1.y); o[6]=f2bf(f1.z); o[7]=f2bf(f1.w);
  ((ushort8*)ws)[dst_idx] = o;
}

// ---------------------------------------------------------------------------
// k_g1: GEMM1 via MFMA. P[j,b] = sum_k W[j,k] x[b,k]. Split-K NZ1=16.
// One 16x16 tile per wave, 10 MFMA steps of k=32. 6144 wave-tasks, 1536 blocks.
// ---------------------------------------------------------------------------
__global__ __launch_bounds__(256) void k_g1(char* __restrict__ ws)
{
  const int wid  = blockIdx.x * 4 + (threadIdx.x >> 6);
  const int l    = threadIdx.x & 63;
  const int z    = wid / 384;
  const int rem  = wid - z * 384;
  const int jt   = rem >> 5;
  const int bt   = rem & 31;
  const int j0   = jt * 16, b0 = bt * 16;

  const bf16x8* WPv = (const bf16x8*)(ws + OFF_WP);
  const bf16x8* xPv = (const bf16x8*)(ws + OFF_XP);
  float* part = (float*)(ws + OFF_PART);

  const int lg = l >> 4, lr = l & 15;
  f32x4 acc = {0.f, 0.f, 0.f, 0.f};

#pragma unroll 2
  for (int s = 0; s < 10; ++s) {
    const int k8 = z * 40 + s * 4 + lg;
    const bf16x8 av = WPv[(size_t)k8 * 192 + j0 + lr];
    const bf16x8 bv = xPv[(size_t)k8 * 512 + b0 + lr];
    acc = __builtin_amdgcn_mfma_f32_16x16x32_bf16(av, bv, acc, 0, 0, 0);
  }

  float* pb = part + (size_t)wid * 256;
#pragma unroll
  for (int r = 0; r < 4; ++r)
    pb[(lg * 4 + r) * 16 + lr] = acc[r];
}

// ---------------------------------------------------------------------------
// k_red1: sum 16 slices. rows<160 -> dtrP bf16 [k8][b][8]; rows 160..175 -> Bc;
// 176..191 -> Cc. 98304 threads = 384 blocks.
// ---------------------------------------------------------------------------
__global__ __launch_bounds__(256) void k_red1(char* __restrict__ ws)
{
  const int e = blockIdx.x * 256 + threadIdx.x;   // (j, b)
  const int j = e >> 9, b = e & 511;
  const int jt = j >> 4, jr = j & 15, bt = b >> 4, bc = b & 15;

  const float* part = (const float*)(ws + OFF_PART);
  float s = 0.f;
#pragma unroll
  for (int z = 0; z < NZ1; ++z)
    s += part[((size_t)(z * 384 + jt * 32 + bt) << 8) + jr * 16 + bc];

  if (j < RK) {
    unsigned short* dtrP = (unsigned short*)(ws + OFF_DTRP);
    dtrP[((size_t)(j >> 3) * 512 + b) * 8 + (j & 7)] = f2bf(s);
  } else if (j < RK + DST) {
    ((float*)(ws + OFF_B))[(size_t)b * DST + (j - RK)] = s;
  } else {
    ((float*)(ws + OFF_C))[(size_t)b * DST + (j - RK - DST)] = s;
  }
}

// ---------------------------------------------------------------------------
// k_g2: dt_pre[b,d] = sum_r dt_r[b,r] Wdt[d,r]; softplus epilogue.
// One 16x16 tile per wave, 5 MFMA steps. 10240 wave-tasks, 2560 blocks.
// ---------------------------------------------------------------------------
__global__ __launch_bounds__(256) void k_g2(
    const float* __restrict__ bdt, char* __restrict__ ws)
{
  const int wid = blockIdx.x * 4 + (threadIdx.x >> 6);
  const int l   = threadIdx.x & 63;
  const int dtile = wid % 320, bt = wid / 320;
  const int d0 = dtile * 16, b0 = bt * 16;

  const bf16x8* dtrPv = (const bf16x8*)(ws + OFF_DTRP);
  const bf16x8* WdtPv = (const bf16x8*)(ws + OFF_WDTP);
  float* dt = (float*)(ws + OFF_DT);

  const int lg = l >> 4, lr = l & 15;
  f32x4 acc = {0.f, 0.f, 0.f, 0.f};

#pragma unroll
  for (int s = 0; s < 5; ++s) {
    const int k8 = s * 4 + lg;
    const bf16x8 av = dtrPv[(size_t)k8 * 512 + b0 + lr];
    const bf16x8 bv = WdtPv[(size_t)k8 * 5120 + d0 + lr];
    acc = __builtin_amdgcn_mfma_f32_16x16x32_bf16(av, bv, acc, 0, 0, 0);
  }

  const int d = d0 + lr;
  const float bias = bdt[d];
#pragma unroll
  for (int r = 0; r < 4; ++r) {
    const int b = b0 + lg * 4 + r;
    const float pre = acc[r] + bias;
    dt[(size_t)b * DIN + d] = (pre > 20.f) ? pre : log1pf(__expf(pre));
  }
}

// ---------------------------------------------------------------------------
// k_y: streaming state update + y, coalesced h (R5 form). 40960 blocks.
// ---------------------------------------------------------------------------
__global__ __launch_bounds__(256) void k_y(
    const float* __restrict__ dt, const float* __restrict__ Bc,
    const float* __restrict__ Cc, const float* __restrict__ A,
    const float* __restrict__ Dp, const float* __restrict__ x,
    const float* __restrict__ h,  float* __restrict__ y)
{
  const int g = blockIdx.x * 64 + (threadIdx.x >> 2);
  const int q = threadIdx.x & 3;
  const int b = g / DIN;
  const int d = g - b * DIN;

  const float dtv = dt[g];
  const float xv  = x[g];
  const float dtx = dtv * xv;

  const float4 h4 = *(const float4*)(h  + (size_t)g * DST + q * 4);
  const float4 A4 = *(const float4*)(A  + (size_t)d * DST + q * 4);
  const float4 B4 = *(const float4*)(Bc + (size_t)b * DST + q * 4);
  const float4 C4 = *(const float4*)(Cc + (size_t)b * DST + q * 4);

  const float dA0 = __expf(A4.x * dtv);
  const float dA1 = __expf(A4.y * dtv);
  const float dA2 = __expf(A4.z * dtv);
  const float dA3 = __expf(A4.w * dtv);
  const float hn0 = fmaf(dA0, h4.x, dtx * B4.x);
  const float hn1 = fmaf(dA1, h4.y, dtx * B4.y);
  const float hn2 = fmaf(dA2, h4.z, dtx * B4.z);
  const float hn3 = fmaf(dA3, h4.w, dtx * B4.w);
  float p = hn0 * C4.x + hn1 * C4.y + hn2 * C4.z + hn3 * C4.w;

  p += __shfl_xor(p, 1);
  p += __shfl_xor(p, 2);
  if (q == 0) y[g] = fmaf(Dp[d], xv, p);
}

extern "C" void kernel_launch(void* const* d_in, const int* in_sizes, int n_in,
                              void* d_out, int out_size, void* d_ws, size_t ws_size,
                              hipStream_t stream) {
  const float* x    = (const float*)d_in[0];
  const float* Wdtr = (const float*)d_in[1];
  const float* Wdt  = (const float*)d_in[2];
  const float* bdt  = (const float*)d_in[3];
  const float* WB   = (const float*)d_in[4];
  const float* WC   = (const float*)d_in[5];
  const float* A    = (const float*)d_in[6];
  const float* Dp   = (const float*)d_in[7];
  const float* h    = (const float*)d_in[8];
  float* y = (float*)d_out;
  char* ws = (char*)d_ws;

  k_prep<<<dim3(2160), 256, 0, stream>>>(x, Wdtr, WB, WC, Wdt, ws);
  k_g1<<<dim3(1536), 256, 0, stream>>>(ws);
  k_red1<<<dim3(384), 256, 0, stream>>>(ws);
  k_g2<<<dim3(2560), 256, 0, stream>>>(bdt, ws);
  k_y<<<dim3((BATCH * DIN) / 64), 256, 0, stream>>>(
      (const float*)(ws + OFF_DT), (const float*)(ws + OFF_B),
      (const float*)(ws + OFF_C), A, Dp, x, h, y);
}

// Round 8
// 56.182 us; speedup vs baseline: 1.8159x; 1.2143x over previous
//
#include <hip/hip_runtime.h>
#include <math.h>

#define BATCH 512
#define DIN   5120
#define DST   16
#define RK    160
#define NJ    192     // 160 dt_rank + 16 B + 16 C
#define NZ1   16      // GEMM1 split-K slices (K=320 each, 10 MFMA steps)

typedef __attribute__((ext_vector_type(8))) __bf16 bf16x8;
typedef __attribute__((ext_vector_type(4))) float f32x4;
typedef __attribute__((ext_vector_type(8))) unsigned short ushort8;

// ws byte offsets (all 16B aligned)
#define OFF_XP    0u          // xP   [640 k8][512 b][8]  bf16
#define OFF_WP    5242880u    // WP   [640 k8][192 j][8]  bf16
#define OFF_WDTP  7208960u    // WdtP [20 k8][5120 d][8]  bf16
#define OFF_PART  8847360u    // part1[6144 task][256]    f32
#define OFF_DTRP  15138816u   // dtrP [20 k8][512 b][8]   bf16
#define OFF_B     15302656u   // Bc   [512][16] f32
#define OFF_C     15335424u   // Cc   [512][16] f32

__device__ __forceinline__ unsigned short f2bf(float f) {
  unsigned int u = __float_as_uint(f);
  u = (u + 0x7FFFu + ((u >> 16) & 1u)) >> 16;   // RNE
  return (unsigned short)u;
}

// ---------------------------------------------------------------------------
// k_prep: pack bf16 operands (xP, WP, WdtP). 2160 blocks.
// ---------------------------------------------------------------------------
#define N1 (512*640)
#define N2 (192*640)
__global__ __launch_bounds__(256) void k_prep(
    const float* __restrict__ x, const float* __restrict__ Wdtr,
    const float* __restrict__ WB, const float* __restrict__ WC,
    const float* __restrict__ Wdt, char* __restrict__ ws)
{
  const int tid = blockIdx.x * 256 + threadIdx.x;
  const float* src; unsigned long long dst_idx;
  if (tid < N1) {
    const int b = tid / 640, k8 = tid - b * 640;
    src = x + (size_t)b * DIN + k8 * 8;
    dst_idx = (OFF_XP >> 4) + (size_t)k8 * 512 + b;
  } else if (tid < N1 + N2) {
    const int i = tid - N1;
    const int j = i / 640, k8 = i - j * 640;
    const float* row;
    if (j < RK)            row = Wdtr + (size_t)j * DIN;
    else if (j < RK + DST) row = WB   + (size_t)(j - RK) * DIN;
    else                   row = WC   + (size_t)(j - RK - DST) * DIN;
    src = row + k8 * 8;
    dst_idx = (OFF_WP >> 4) + (size_t)k8 * 192 + j;
  } else {
    const int i = tid - N1 - N2;          // < 5120*20
    const int d = i / 20, k8 = i - d * 20;
    src = Wdt + (size_t)d * RK + k8 * 8;
    dst_idx = (OFF_WDTP >> 4) + (size_t)k8 * 5120 + d;
  }
  const float4 f0 = *(const float4*)(src);
  const float4 f1 = *(const float4*)(src + 4);
  ushort8 o;
  o[0]=f2bf(f0.x); o[1]=f2bf(f0.y); o[2]=f2bf(f0.z); o[3]=f2bf(f0.w);
  o[4]=f2bf(f1.x); o[5]=f2bf(f1.y); o[6]=f2bf(f1.z); o[7]=f2bf(f1.w);
  ((ushort8*)ws)[dst_idx] = o;
}

// ---------------------------------------------------------------------------
// k_g1: GEMM1 via MFMA. P[j,b] = sum_k W[j,k] x[b,k]. Split-K NZ1=16.
// One 16x16 tile per wave, 10 MFMA steps of k=32. 1536 blocks.
// ---------------------------------------------------------------------------
__global__ __launch_bounds__(256) void k_g1(char* __restrict__ ws)
{
  const int wid  = blockIdx.x * 4 + (threadIdx.x >> 6);
  const int l    = threadIdx.x & 63;
  const int z    = wid / 384;
  const int rem  = wid - z * 384;
  const int jt   = rem >> 5;
  const int bt   = rem & 31;
  const int j0   = jt * 16, b0 = bt * 16;

  const bf16x8* WPv = (const bf16x8*)(ws + OFF_WP);
  const bf16x8* xPv = (const bf16x8*)(ws + OFF_XP);
  float* part = (float*)(ws + OFF_PART);

  const int lg = l >> 4, lr = l & 15;
  f32x4 acc = {0.f, 0.f, 0.f, 0.f};

#pragma unroll 2
  for (int s = 0; s < 10; ++s) {
    const int k8 = z * 40 + s * 4 + lg;
    const bf16x8 av = WPv[(size_t)k8 * 192 + j0 + lr];
    const bf16x8 bv = xPv[(size_t)k8 * 512 + b0 + lr];
    acc = __builtin_amdgcn_mfma_f32_16x16x32_bf16(av, bv, acc, 0, 0, 0);
  }

  float* pb = part + (size_t)wid * 256;
#pragma unroll
  for (int r = 0; r < 4; ++r)
    pb[(lg * 4 + r) * 16 + lr] = acc[r];
}

// ---------------------------------------------------------------------------
// k_red1: sum 16 slices -> dtrP (bf16 packed) / Bc / Cc. 384 blocks.
// ---------------------------------------------------------------------------
__global__ __launch_bounds__(256) void k_red1(char* __restrict__ ws)
{
  const int e = blockIdx.x * 256 + threadIdx.x;   // (j, b)
  const int j = e >> 9, b = e & 511;
  const int jt = j >> 4, jr = j & 15, bt = b >> 4, bc = b & 15;

  const float* part = (const float*)(ws + OFF_PART);
  float s = 0.f;
#pragma unroll
  for (int z = 0; z < NZ1; ++z)
    s += part[((size_t)(z * 384 + jt * 32 + bt) << 8) + jr * 16 + bc];

  if (j < RK) {
    unsigned short* dtrP = (unsigned short*)(ws + OFF_DTRP);
    dtrP[((size_t)(j >> 3) * 512 + b) * 8 + (j & 7)] = f2bf(s);
  } else if (j < RK + DST) {
    ((float*)(ws + OFF_B))[(size_t)b * DST + (j - RK)] = s;
  } else {
    ((float*)(ws + OFF_C))[(size_t)b * DST + (j - RK - DST)] = s;
  }
}

// ---------------------------------------------------------------------------
// k_g2y: FUSED dt-GEMM + softplus + state update + y.
// One wave per 16b x 16d tile (10240 wave-tasks, 2560 blocks):
//   phase 1: 5-step MFMA -> dt tile -> softplus -> LDS [16b][16d]
//   phase 2: quad Q owns d=d0+Q; iterate j=0..15 over b. h reads: wave covers
//            ((b0+j)*DIN + d0..d0+15)*16 floats = 1KB contiguous. A/Dp hoisted.
// ---------------------------------------------------------------------------
__global__ __launch_bounds__(256) void k_g2y(
    const float* __restrict__ bdt, const float* __restrict__ A,
    const float* __restrict__ Dp,  const float* __restrict__ x,
    const float* __restrict__ h,   float* __restrict__ y,
    char* __restrict__ ws)
{
  __shared__ float sDT[4][16][17];
  const int w = threadIdx.x >> 6;
  const int l = threadIdx.x & 63;
  const int wid = blockIdx.x * 4 + w;
  const int dtile = wid % 320, btile = wid / 320;
  const int d0 = dtile * 16, b0 = btile * 16;

  const bf16x8* dtrPv = (const bf16x8*)(ws + OFF_DTRP);
  const bf16x8* WdtPv = (const bf16x8*)(ws + OFF_WDTP);
  const float*  Bc    = (const float*)(ws + OFF_B);
  const float*  Cc    = (const float*)(ws + OFF_C);

  const int lg = l >> 4, lr = l & 15;
  f32x4 acc = {0.f, 0.f, 0.f, 0.f};
#pragma unroll
  for (int s = 0; s < 5; ++s) {
    const int k8 = s * 4 + lg;
    const bf16x8 av = dtrPv[(size_t)k8 * 512 + b0 + lr];
    const bf16x8 bv = WdtPv[(size_t)k8 * 5120 + d0 + lr];
    acc = __builtin_amdgcn_mfma_f32_16x16x32_bf16(av, bv, acc, 0, 0, 0);
  }
  const float bias = bdt[d0 + lr];
#pragma unroll
  for (int r = 0; r < 4; ++r) {
    const float pre = acc[r] + bias;   // dt for (b=b0+lg*4+r, d=d0+lr)
    sDT[w][lg * 4 + r][lr] = (pre > 20.f) ? pre : log1pf(__expf(pre));
  }
  __syncthreads();

  // phase 2
  const int q = l & 3;      // state group (4 states each)
  const int Q = l >> 2;     // quad index -> d offset
  const int d = d0 + Q;
  const float4 A4 = *(const float4*)(A + (size_t)d * DST + q * 4);
  const float  Dv = Dp[d];

#pragma unroll 4
  for (int j = 0; j < 16; ++j) {
    const int b = b0 + j;
    const int g = b * DIN + d;
    const float dtv = sDT[w][j][Q];
    const float xv  = x[g];
    const float dtx = dtv * xv;

    const float4 h4 = *(const float4*)(h  + (size_t)g * DST + q * 4);
    const float4 B4 = *(const float4*)(Bc + (size_t)b * DST + q * 4);
    const float4 C4 = *(const float4*)(Cc + (size_t)b * DST + q * 4);

    const float dA0 = __expf(A4.x * dtv);
    const float dA1 = __expf(A4.y * dtv);
    const float dA2 = __expf(A4.z * dtv);
    const float dA3 = __expf(A4.w * dtv);
    const float hn0 = fmaf(dA0, h4.x, dtx * B4.x);
    const float hn1 = fmaf(dA1, h4.y, dtx * B4.y);
    const float hn2 = fmaf(dA2, h4.z, dtx * B4.z);
    const float hn3 = fmaf(dA3, h4.w, dtx * B4.w);
    float p = hn0 * C4.x + hn1 * C4.y + hn2 * C4.z + hn3 * C4.w;

    p += __shfl_xor(p, 1);
    p += __shfl_xor(p, 2);
    if (q == 0) y[g] = fmaf(Dv, xv, p);
  }
}

extern "C" void kernel_launch(void* const* d_in, const int* in_sizes, int n_in,
                              void* d_out, int out_size, void* d_ws, size_t ws_size,
                              hipStream_t stream) {
  const float* x    = (const float*)d_in[0];
  const float* Wdtr = (const float*)d_in[1];
  const float* Wdt  = (const float*)d_in[2];
  const float* bdt  = (const float*)d_in[3];
  const float* WB   = (const float*)d_in[4];
  const float* WC   = (const float*)d_in[5];
  const float* A    = (const float*)d_in[6];
  const float* Dp   = (const float*)d_in[7];
  const float* h    = (const float*)d_in[8];
  float* y = (float*)d_out;
  char* ws = (char*)d_ws;

  k_prep<<<dim3(2160), 256, 0, stream>>>(x, Wdtr, WB, WC, Wdt, ws);
  k_g1<<<dim3(1536), 256, 0, stream>>>(ws);
  k_red1<<<dim3(384), 256, 0, stream>>>(ws);
  k_g2y<<<dim3(2560), 256, 0, stream>>>(bdt, A, Dp, x, h, y, ws);
}